// Round 9
// baseline (181.509 us; speedup 1.0000x reference)
//
#include <hip/hip_runtime.h>

// TimeDomainCochleagram: exact chunked scan, 256 segments x 375 samples,
// PACKED: 128 threads/block, lane g runs segments (g, g+128) as a float2
// SIMD pair (v_pk_fma_f32). (g+128)&7 == g&7 -> both components share the
// same pooling phase; only output index differs (+2000).
//   setup (1 block, fp64): per channel, Mk = A^(375*2^k), k=0..7 -> d_ws.
//   main: pass 1 (zero-state, packed) -> fp64 Kogge-Stone over 256 end
//   states (8 levels, LDS ping-pong; thread g owns rows g and g+128) ->
//   pass 2 (exact init, relu + mean-pool(24), boundary once per 3 samples).

typedef float f32x2 __attribute__((ext_vector_type(2)));

#define NCH  40
#define NB   8
#define TS   96000
#define DOWN 24
#define NSEG 256
#define SEG  375
#define HALF 128
#define TD   4000
#define NLVL 8
#define INV24 (1.0f/24.0f)

typedef double DMat[4][4][2][2];   // 2x2 blocks; only j<=i used

__device__ __forceinline__ void dmatcopy(DMat dst, const DMat src) {
    #pragma unroll
    for (int i = 0; i < 4; i++)
        #pragma unroll
        for (int j = 0; j < 4; j++) if (j <= i)
            #pragma unroll
            for (int r = 0; r < 2; r++)
                #pragma unroll
                for (int c = 0; c < 2; c++)
                    dst[i][j][r][c] = src[i][j][r][c];
}

__device__ __forceinline__ void dmatmul(DMat C, const DMat A, const DMat B) {
    #pragma unroll
    for (int i = 0; i < 4; i++)
        #pragma unroll
        for (int j = 0; j < 4; j++) if (j <= i)
            #pragma unroll
            for (int r = 0; r < 2; r++)
                #pragma unroll
                for (int c = 0; c < 2; c++) {
                    double acc = 0.0;
                    #pragma unroll
                    for (int k = 0; k < 4; k++) if (k >= j && k <= i)
                        #pragma unroll
                        for (int q = 0; q < 2; q++)
                            acc += A[i][k][r][q] * B[k][j][q][c];
                    C[i][j][r][c] = acc;
                }
}

// ---------- setup: Mk = A^(375*2^k), k=0..7, fp64 (verbatim from round 7) ----------
__global__ __launch_bounds__(64)
void cochlea_setup(const float* __restrict__ fcoefs, double* __restrict__ ws)
{
    const int c = (int)threadIdx.x;
    if (c >= NCH) return;
    const float* fc = fcoefs + c * 10;
    const double a0  = (double)fc[0];
    const double n11 = (double)fc[2], n12 = (double)fc[3], n13 = (double)fc[4];
    const double nd1 = -(double)fc[7], nd2 = -(double)fc[8];

    double s[8];
    auto step0 = [&]() {     // one cascade step, x = 0, fp64
        double y0 = s[0];
        s[0] = nd1 * y0 + s[1];
        s[1] = nd2 * y0;
        double y1 = a0 * y0 + s[2];
        s[2] = nd1 * y1 + (n11 * y0 + s[3]);
        s[3] = nd2 * y1;
        double y2 = a0 * y1 + s[4];
        s[4] = nd1 * y2 + (n12 * y1 + s[5]);
        s[5] = nd2 * y2;
        double y3 = a0 * y2 + s[6];
        s[6] = nd1 * y3 + (n13 * y2 + s[7]);
        s[7] = nd2 * y3;
    };

    DMat A, P, T;
    #pragma unroll
    for (int j = 0; j < 8; j++) {
        #pragma unroll
        for (int i = 0; i < 8; i++) s[i] = (i == j) ? 1.0 : 0.0;
        step0();
        #pragma unroll
        for (int i = 0; i < 8; i++)
            if ((i >> 1) >= (j >> 1))
                A[i >> 1][j >> 1][i & 1][j & 1] = s[i];
    }

    // P = A^375; 375 = 0b101110111 -> tail bits after MSB: 0,1,1,1,0,1,1,1
    dmatcopy(P, A);
    const int bits[8] = {0, 1, 1, 1, 0, 1, 1, 1};
    #pragma unroll
    for (int t = 0; t < 8; t++) {
        dmatmul(T, P, P);
        if (bits[t]) dmatmul(P, T, A);
        else         dmatcopy(P, T);
    }

    // store levels: Mk = P^(2^k); linear idx = (rb*(rb+1)/2+cb)*4 + ri*2 + ci
    double* o = ws + (size_t)c * (NLVL * 40);
    for (int k = 0; k < NLVL; k++) {
        #pragma unroll
        for (int rb = 0; rb < 4; rb++)
            #pragma unroll
            for (int cb = 0; cb < 4; cb++) if (cb <= rb)
                #pragma unroll
                for (int ri = 0; ri < 2; ri++)
                    #pragma unroll
                    for (int ci = 0; ci < 2; ci++)
                        o[k * 40 + (rb * (rb + 1) / 2 + cb) * 4 + ri * 2 + ci] = P[rb][cb][ri][ci];
        if (k < NLVL - 1) { dmatmul(T, P, P); dmatcopy(P, T); }
    }
}

// ---------- main: packed pass1 -> dp Kogge-Stone -> packed pass2 ----------
__global__ __launch_bounds__(128, 1)
void cochlea_main(const float* __restrict__ x,
                  const float* __restrict__ fcoefs,
                  const double* __restrict__ ws,
                  float* __restrict__ out)
{
    const int b = (int)blockIdx.x;
    const int c = (int)blockIdx.y;
    const int g = (int)threadIdx.x;        // 0..127; owns segments g and g+128

    const float* fc  = fcoefs + c * 10;
    const float a0   = fc[0];
    const float gain = fc[9];
    const float n00  = a0 / gain;
    const float n10  = fc[1] / gain;

    // packed (splat) coefficients
    const f32x2 va0  = {a0, a0};
    const f32x2 vn00 = {n00, n00};
    const f32x2 vn10 = {n10, n10};
    const f32x2 vn11 = {fc[2], fc[2]};
    const f32x2 vn12 = {fc[3], fc[3]};
    const f32x2 vn13 = {fc[4], fc[4]};
    const f32x2 vnd1 = {-fc[7], -fc[7]};
    const f32x2 vnd2 = {-fc[8], -fc[8]};
    const f32x2 vz   = {0.f, 0.f};

    f32x2 S[8];
    // one packed time-step: two independent segments per lane (a2==0 form)
    auto stepp = [&](f32x2 xv) -> f32x2 {
        f32x2 y0 = __builtin_elementwise_fma(vn00, xv, S[0]);
        S[0] = __builtin_elementwise_fma(vnd1, y0, __builtin_elementwise_fma(vn10, xv, S[1]));
        S[1] = vnd2 * y0;
        f32x2 y1 = __builtin_elementwise_fma(va0, y0, S[2]);
        S[2] = __builtin_elementwise_fma(vnd1, y1, __builtin_elementwise_fma(vn11, y0, S[3]));
        S[3] = vnd2 * y1;
        f32x2 y2 = __builtin_elementwise_fma(va0, y1, S[4]);
        S[4] = __builtin_elementwise_fma(vnd1, y2, __builtin_elementwise_fma(vn12, y1, S[5]));
        S[5] = vnd2 * y2;
        f32x2 y3 = __builtin_elementwise_fma(va0, y2, S[6]);
        S[6] = __builtin_elementwise_fma(vnd1, y3, __builtin_elementwise_fma(vn13, y2, S[7]));
        S[7] = vnd2 * y3;
        return y3;
    };
    auto mk2 = [](float u, float v) { f32x2 r; r.x = u; r.y = v; return r; };

    // two segment streams: 25 macro-groups of 15 samples (5 float3) each
    const float* xb = x + (size_t)b * TS;
    const float3* xa3 = reinterpret_cast<const float3*>(xb + (size_t)g * SEG);
    const float3* xc3 = reinterpret_cast<const float3*>(xb + (size_t)(g + HALF) * SEG);
    float3 aA[5], cA[5], aB[5], cB[5];
    auto loadg = [&](float3 (&fa)[5], float3 (&fb)[5], int m) {
        #pragma unroll
        for (int q = 0; q < 5; q++) { fa[q] = xa3[m * 5 + q]; fb[q] = xc3[m * 5 + q]; }
    };

    // ---- pass 1: zero state -> packed end states ----
    #pragma unroll
    for (int i = 0; i < 8; i++) S[i] = vz;
    auto c1 = [&](const float3 (&fa)[5], const float3 (&fb)[5]) {
        #pragma unroll
        for (int q = 0; q < 5; q++) {
            stepp(mk2(fa[q].x, fb[q].x));
            stepp(mk2(fa[q].y, fb[q].y));
            stepp(mk2(fa[q].z, fb[q].z));
        }
    };
    loadg(aA, cA, 0);
    for (int p = 0; p < 12; p++) {
        loadg(aB, cB, 2 * p + 1);
        c1(aA, cA);
        loadg(aA, cA, 2 * p + 2);
        c1(aB, cB);
    }
    c1(aA, cA);   // macro-group 24

    // ---- dp Kogge-Stone inclusive scan over 256 end states ----
    __shared__ double tk[2][NSEG][9];   // pad row to 9 dbl
    double tdx[8], tdy[8];
    #pragma unroll
    for (int i = 0; i < 8; i++) { tdx[i] = (double)S[i].x; tdy[i] = (double)S[i].y; }
    int cur = 0;
    #pragma unroll
    for (int i = 0; i < 8; i++) { tk[0][g][i] = tdx[i]; tk[0][g + HALF][i] = tdy[i]; }
    __syncthreads();

    const double* wsc = ws + (size_t)c * (NLVL * 40);
    for (int k = 0; k < NLVL; k++) {
        double M[40];
        #pragma unroll
        for (int q = 0; q < 40; q++) M[q] = wsc[k * 40 + q];

        auto matvec = [&](double (&td)[8], int src) {   // td += M * tk[cur][src]
            double pr[8];
            #pragma unroll
            for (int i = 0; i < 8; i++) pr[i] = tk[cur][src][i];
            double nt[8];
            #pragma unroll
            for (int rb = 0; rb < 4; rb++)
                #pragma unroll
                for (int ri = 0; ri < 2; ri++) {
                    double acc = td[2 * rb + ri];
                    #pragma unroll
                    for (int cb = 0; cb < 4; cb++) if (cb <= rb)
                        #pragma unroll
                        for (int ci = 0; ci < 2; ci++)
                            acc += M[(rb * (rb + 1) / 2 + cb) * 4 + ri * 2 + ci] * pr[2 * cb + ci];
                    nt[2 * rb + ri] = acc;
                }
            #pragma unroll
            for (int i = 0; i < 8; i++) td[i] = nt[i];
        };

        const int d = 1 << k;
        if (g - d >= 0) matvec(tdx, g - d);          // row g (g-d<0 -> pass-through)
        matvec(tdy, g + HALF - d);                   // row g+128: src >= 0 always

        #pragma unroll
        for (int i = 0; i < 8; i++) { tk[cur ^ 1][g][i] = tdx[i]; tk[cur ^ 1][g + HALF][i] = tdy[i]; }
        __syncthreads();
        cur ^= 1;
    }

    // exclusive: init for segment r = inclusive[r-1]; segment 0 = zero
    #pragma unroll
    for (int i = 0; i < 8; i++) {
        S[i].x = (g == 0) ? 0.f : (float)tk[cur][g - 1][i];
        S[i].y = (float)tk[cur][g + HALF - 1][i];
    }

    // ---- pass 2: exact init, relu + mean-pool(24), 3-sample boundary logic.
    // Both components share g8 = g&7 == (g+128)&7 -> identical control flow.
    const int g8      = g & 7;
    const int offset  = (15 * g8) % 24;          // segment start mod 24
    const int r       = (24 - offset) % 24;      // head length (samples)
    const bool hashead = (offset != 0);
    const int hh      = hashead ? 1 : 0;
    const int w0      = (SEG * g + r) / 24;      // component x; comp y = +2000
    const int ph      = (1 + 5 * g8) & 7;        // boundary iff (jj + ph) % 8 == 0
    float* outp = out + ((size_t)b * NCH + c) * TD;

    f32x2 acc = vz, head = vz;
    int kb = 0;

    auto c2 = [&](const float3 (&fa)[5], const float3 (&fb)[5], int m) {
        #pragma unroll
        for (int q = 0; q < 5; q++) {
            acc += __builtin_elementwise_max(stepp(mk2(fa[q].x, fb[q].x)), vz);
            acc += __builtin_elementwise_max(stepp(mk2(fa[q].y, fb[q].y)), vz);
            acc += __builtin_elementwise_max(stepp(mk2(fa[q].z, fb[q].z)), vz);
            int jj = m * 5 + q;
            if (((jj + ph) & 7) == 0) {          // window boundary for this lane
                bool ishead = hashead && (kb == 0);
                if (ishead) head = acc;
                else {
                    int idx = w0 + kb - hh;
                    outp[idx]        = acc.x * INV24;
                    outp[idx + 2000] = acc.y * INV24;
                }
                kb++;
                acc = vz;
            }
        }
    };
    loadg(aA, cA, 0);
    for (int p = 0; p < 12; p++) {
        loadg(aB, cB, 2 * p + 1);
        c2(aA, cA, 2 * p);
        loadg(aA, cA, 2 * p + 2);
        c2(aB, cB, 2 * p + 1);
    }
    c2(aA, cA, 24);

    // straddled windows: my tails + right neighbor's heads. g8==7 lanes have
    // zero tail (covers g=63 and g+128=191,255) -> shfl never crosses a wave.
    float hx = __shfl_down(head.x, 1, 64);
    float hy = __shfl_down(head.y, 1, 64);
    if (g8 != 7) {
        int idx = w0 + kb - hh;
        outp[idx]        = (acc.x + hx) * INV24;
        outp[idx + 2000] = (acc.y + hy) * INV24;
    }
}

extern "C" void kernel_launch(void* const* d_in, const int* in_sizes, int n_in,
                              void* d_out, int out_size, void* d_ws, size_t ws_size,
                              hipStream_t stream) {
    const float* x      = (const float*)d_in[0];   // (8, 96000) f32
    const float* fcoefs = (const float*)d_in[1];   // (40, 10)  f32
    float* out = (float*)d_out;                    // (8, 40, 4000) f32
    double* ws = (double*)d_ws;                    // 40*8*40 doubles = 100 KB

    cochlea_setup<<<1, 64, 0, stream>>>(fcoefs, ws);
    dim3 grid(NB, NCH);                            // 320 blocks x 2 waves
    cochlea_main<<<grid, 128, 0, stream>>>(x, fcoefs, ws, out);
}

// Round 13
// 113.580 us; speedup vs baseline: 1.5981x; 1.5981x over previous
//
#include <hip/hip_runtime.h>

// TimeDomainCochleagram: exact chunked scan, 256 segments x 375 samples,
// CHANNEL-PACKED: block = (batch b, channel-pair cp) handles channels
// cp and cp+20. 256 threads; lane g owns segment g for BOTH channels as an
// f32x2 (v_pk_fma_f32). Same sample feeds both components -> ONE load
// stream (round-7-proven shape, no spill), 2x compute per instruction.
//   setup (1 block, fp64): per channel, Mk = A^(375*2^k), k=0..7 -> d_ws.
//   main: packed pass 1 -> TWO sequential fp64 Kogge-Stone scans (channel
//   A then B, one shared LDS ping-pong; scan-phase register pressure equals
//   round 7's) -> packed pass 2 (relu + mean-pool(24), boundary once per
//   3 samples, straddles via shfl_down, never crossing a wave).

typedef float f32x2 __attribute__((ext_vector_type(2)));

#define NCH  40
#define NB   8
#define NCP  20            // channel pairs: (cp, cp+20)
#define TS   96000
#define DOWN 24
#define NSEG 256
#define SEG  375
#define TD   4000
#define NLVL 8
#define INV24 (1.0f/24.0f)

typedef double DMat[4][4][2][2];   // 2x2 blocks; only j<=i used

__device__ __forceinline__ void dmatcopy(DMat dst, const DMat src) {
    #pragma unroll
    for (int i = 0; i < 4; i++)
        #pragma unroll
        for (int j = 0; j < 4; j++) if (j <= i)
            #pragma unroll
            for (int r = 0; r < 2; r++)
                #pragma unroll
                for (int c = 0; c < 2; c++)
                    dst[i][j][r][c] = src[i][j][r][c];
}

__device__ __forceinline__ void dmatmul(DMat C, const DMat A, const DMat B) {
    #pragma unroll
    for (int i = 0; i < 4; i++)
        #pragma unroll
        for (int j = 0; j < 4; j++) if (j <= i)
            #pragma unroll
            for (int r = 0; r < 2; r++)
                #pragma unroll
                for (int c = 0; c < 2; c++) {
                    double acc = 0.0;
                    #pragma unroll
                    for (int k = 0; k < 4; k++) if (k >= j && k <= i)
                        #pragma unroll
                        for (int q = 0; q < 2; q++)
                            acc += A[i][k][r][q] * B[k][j][q][c];
                    C[i][j][r][c] = acc;
                }
}

// ---------- setup: Mk = A^(375*2^k), k=0..7, fp64 (proven, verbatim) ----------
__global__ __launch_bounds__(64)
void cochlea_setup(const float* __restrict__ fcoefs, double* __restrict__ ws)
{
    const int c = (int)threadIdx.x;
    if (c >= NCH) return;
    const float* fc = fcoefs + c * 10;
    const double a0  = (double)fc[0];
    const double n11 = (double)fc[2], n12 = (double)fc[3], n13 = (double)fc[4];
    const double nd1 = -(double)fc[7], nd2 = -(double)fc[8];

    double s[8];
    auto step0 = [&]() {     // one cascade step, x = 0, fp64
        double y0 = s[0];
        s[0] = nd1 * y0 + s[1];
        s[1] = nd2 * y0;
        double y1 = a0 * y0 + s[2];
        s[2] = nd1 * y1 + (n11 * y0 + s[3]);
        s[3] = nd2 * y1;
        double y2 = a0 * y1 + s[4];
        s[4] = nd1 * y2 + (n12 * y1 + s[5]);
        s[5] = nd2 * y2;
        double y3 = a0 * y2 + s[6];
        s[6] = nd1 * y3 + (n13 * y2 + s[7]);
        s[7] = nd2 * y3;
    };

    DMat A, P, T;
    #pragma unroll
    for (int j = 0; j < 8; j++) {
        #pragma unroll
        for (int i = 0; i < 8; i++) s[i] = (i == j) ? 1.0 : 0.0;
        step0();
        #pragma unroll
        for (int i = 0; i < 8; i++)
            if ((i >> 1) >= (j >> 1))
                A[i >> 1][j >> 1][i & 1][j & 1] = s[i];
    }

    // P = A^375; 375 = 0b101110111 -> tail bits after MSB: 0,1,1,1,0,1,1,1
    dmatcopy(P, A);
    const int bits[8] = {0, 1, 1, 1, 0, 1, 1, 1};
    #pragma unroll
    for (int t = 0; t < 8; t++) {
        dmatmul(T, P, P);
        if (bits[t]) dmatmul(P, T, A);
        else         dmatcopy(P, T);
    }

    // store levels: Mk = P^(2^k); linear idx = (rb*(rb+1)/2+cb)*4 + ri*2 + ci
    double* o = ws + (size_t)c * (NLVL * 40);
    for (int k = 0; k < NLVL; k++) {
        #pragma unroll
        for (int rb = 0; rb < 4; rb++)
            #pragma unroll
            for (int cb = 0; cb < 4; cb++) if (cb <= rb)
                #pragma unroll
                for (int ri = 0; ri < 2; ri++)
                    #pragma unroll
                    for (int ci = 0; ci < 2; ci++)
                        o[k * 40 + (rb * (rb + 1) / 2 + cb) * 4 + ri * 2 + ci] = P[rb][cb][ri][ci];
        if (k < NLVL - 1) { dmatmul(T, P, P); dmatcopy(P, T); }
    }
}

// ---------- main: packed pass1 -> 2x sequential fp64 KS scan -> packed pass2 ----------
__global__ __launch_bounds__(256, 1)
void cochlea_main(const float* __restrict__ x,
                  const float* __restrict__ fcoefs,
                  const double* __restrict__ ws,
                  float* __restrict__ out)
{
    const int b  = (int)blockIdx.x;
    const int cp = (int)blockIdx.y;          // channel pair: (cp, cp+20)
    const int g  = (int)threadIdx.x;         // segment index 0..255

    const float* fA = fcoefs + cp * 10;
    const float* fB = fcoefs + (cp + NCP) * 10;

    // packed coefficients {channel A, channel B}
    auto mk2 = [](float u, float v) { f32x2 r; r.x = u; r.y = v; return r; };
    const f32x2 va0  = mk2(fA[0], fB[0]);
    const f32x2 vn00 = mk2(fA[0] / fA[9], fB[0] / fB[9]);
    const f32x2 vn10 = mk2(fA[1] / fA[9], fB[1] / fB[9]);
    const f32x2 vn11 = mk2(fA[2], fB[2]);
    const f32x2 vn12 = mk2(fA[3], fB[3]);
    const f32x2 vn13 = mk2(fA[4], fB[4]);
    const f32x2 vnd1 = mk2(-fA[7], -fB[7]);
    const f32x2 vnd2 = mk2(-fA[8], -fB[8]);
    const f32x2 vz   = mk2(0.f, 0.f);

    f32x2 S[8];
    // one packed time-step: same sample x for both channels (a2==0 form)
    auto stepp = [&](float xu) -> f32x2 {
        f32x2 xv = mk2(xu, xu);
        f32x2 y0 = __builtin_elementwise_fma(vn00, xv, S[0]);
        S[0] = __builtin_elementwise_fma(vnd1, y0, __builtin_elementwise_fma(vn10, xv, S[1]));
        S[1] = vnd2 * y0;
        f32x2 y1 = __builtin_elementwise_fma(va0, y0, S[2]);
        S[2] = __builtin_elementwise_fma(vnd1, y1, __builtin_elementwise_fma(vn11, y0, S[3]));
        S[3] = vnd2 * y1;
        f32x2 y2 = __builtin_elementwise_fma(va0, y1, S[4]);
        S[4] = __builtin_elementwise_fma(vnd1, y2, __builtin_elementwise_fma(vn12, y1, S[5]));
        S[5] = vnd2 * y2;
        f32x2 y3 = __builtin_elementwise_fma(va0, y2, S[6]);
        S[6] = __builtin_elementwise_fma(vnd1, y3, __builtin_elementwise_fma(vn13, y2, S[7]));
        S[7] = vnd2 * y3;
        return y3;
    };

    // ONE load stream (round-7 shape): 25 macro-groups of 15 samples (5 float3)
    const float3* xb3 = reinterpret_cast<const float3*>(x + (size_t)b * TS + (size_t)g * SEG);
    float3 bA[5], bB[5];
    auto loadg = [&](float3 (&bf)[5], int m) {
        #pragma unroll
        for (int q = 0; q < 5; q++) bf[q] = xb3[m * 5 + q];
    };

    // ---- pass 1: zero state -> packed end state ----
    #pragma unroll
    for (int i = 0; i < 8; i++) S[i] = vz;
    auto c1 = [&](const float3 (&bf)[5]) {
        #pragma unroll
        for (int q = 0; q < 5; q++) { stepp(bf[q].x); stepp(bf[q].y); stepp(bf[q].z); }
    };
    loadg(bA, 0);
    for (int p = 0; p < 12; p++) {
        loadg(bB, 2 * p + 1);
        c1(bA);
        loadg(bA, 2 * p + 2);
        c1(bB);
    }
    c1(bA);   // macro-group 24

    // ---- two sequential fp64 Kogge-Stone scans (shared LDS ping-pong) ----
    __shared__ double tk[2][NSEG][9];   // pad row to 9 dbl
    float iA[8], iB[8];

    auto run_scan = [&](const double* wsc, const double (&ei)[8], float (&oi)[8]) {
        int cur = 0;
        #pragma unroll
        for (int i = 0; i < 8; i++) tk[0][g][i] = ei[i];
        __syncthreads();
        double td[8];
        #pragma unroll
        for (int i = 0; i < 8; i++) td[i] = ei[i];
        for (int k = 0; k < NLVL; k++) {
            double M[40];
            #pragma unroll
            for (int q = 0; q < 40; q++) M[q] = wsc[k * 40 + q];
            const int d = 1 << k;
            if (g >= d) {
                double pr[8];
                #pragma unroll
                for (int i = 0; i < 8; i++) pr[i] = tk[cur][g - d][i];
                double nt[8];
                #pragma unroll
                for (int rb = 0; rb < 4; rb++)
                    #pragma unroll
                    for (int ri = 0; ri < 2; ri++) {
                        double acc = td[2 * rb + ri];
                        #pragma unroll
                        for (int cb = 0; cb < 4; cb++) if (cb <= rb)
                            #pragma unroll
                            for (int ci = 0; ci < 2; ci++)
                                acc += M[(rb * (rb + 1) / 2 + cb) * 4 + ri * 2 + ci] * pr[2 * cb + ci];
                        nt[2 * rb + ri] = acc;
                    }
                #pragma unroll
                for (int i = 0; i < 8; i++) td[i] = nt[i];
            }
            #pragma unroll
            for (int i = 0; i < 8; i++) tk[cur ^ 1][g][i] = td[i];
            __syncthreads();
            cur ^= 1;
        }
        // exclusive: init for segment g = inclusive[g-1]; segment 0 = zero
        #pragma unroll
        for (int i = 0; i < 8; i++) oi[i] = (g == 0) ? 0.f : (float)tk[cur][g - 1][i];
        __syncthreads();    // protect tk before the next scan reuses it
    };

    {
        double e[8];
        #pragma unroll
        for (int i = 0; i < 8; i++) e[i] = (double)S[i].x;
        run_scan(ws + (size_t)cp * (NLVL * 40), e, iA);
        #pragma unroll
        for (int i = 0; i < 8; i++) e[i] = (double)S[i].y;
        run_scan(ws + (size_t)(cp + NCP) * (NLVL * 40), e, iB);
    }

    #pragma unroll
    for (int i = 0; i < 8; i++) S[i] = mk2(iA[i], iB[i]);

    // ---- pass 2: exact init, relu + mean-pool(24), 3-sample boundary logic ----
    const int g8      = g & 7;
    const int offset  = (15 * g8) % 24;          // segment start mod 24
    const int r       = (24 - offset) % 24;      // head length (samples)
    const bool hashead = (offset != 0);
    const int hh      = hashead ? 1 : 0;
    const int w0      = (SEG * g + r) / 24;      // first own full-window index
    const int ph      = (1 + 5 * g8) & 7;        // boundary iff (jj + ph) % 8 == 0
    float* outA = out + ((size_t)b * NCH + cp) * TD;
    float* outB = out + ((size_t)b * NCH + cp + NCP) * TD;

    f32x2 acc = vz, head = vz;
    int kb = 0;

    auto c2 = [&](const float3 (&bf)[5], int m) {
        #pragma unroll
        for (int q = 0; q < 5; q++) {
            float3 v = bf[q];
            acc += __builtin_elementwise_max(stepp(v.x), vz);
            acc += __builtin_elementwise_max(stepp(v.y), vz);
            acc += __builtin_elementwise_max(stepp(v.z), vz);
            int jj = m * 5 + q;
            if (((jj + ph) & 7) == 0) {          // window boundary for this lane
                bool ishead = hashead && (kb == 0);
                if (ishead) head = acc;
                else {
                    int idx = w0 + kb - hh;
                    outA[idx] = acc.x * INV24;
                    outB[idx] = acc.y * INV24;
                }
                kb++;
                acc = vz;
            }
        }
    };
    loadg(bA, 0);
    for (int p = 0; p < 12; p++) {
        loadg(bB, 2 * p + 1);
        c2(bA, 2 * p);
        loadg(bA, 2 * p + 2);
        c2(bB, 2 * p + 1);
    }
    c2(bA, 24);

    // straddled window: my tail + right neighbor's head. g8==7 lanes (incl.
    // 63/127/191/255) have zero tail -> shfl never crosses a wave boundary.
    float hx = __shfl_down(head.x, 1, 64);
    float hy = __shfl_down(head.y, 1, 64);
    if (g8 != 7) {
        int idx = w0 + kb - hh;
        outA[idx] = (acc.x + hx) * INV24;
        outB[idx] = (acc.y + hy) * INV24;
    }
}

extern "C" void kernel_launch(void* const* d_in, const int* in_sizes, int n_in,
                              void* d_out, int out_size, void* d_ws, size_t ws_size,
                              hipStream_t stream) {
    const float* x      = (const float*)d_in[0];   // (8, 96000) f32
    const float* fcoefs = (const float*)d_in[1];   // (40, 10)  f32
    float* out = (float*)d_out;                    // (8, 40, 4000) f32
    double* ws = (double*)d_ws;                    // 40*8*40 doubles = 100 KB

    cochlea_setup<<<1, 64, 0, stream>>>(fcoefs, ws);
    dim3 grid(NB, NCP);                            // 160 blocks x 4 waves
    cochlea_main<<<grid, 256, 0, stream>>>(x, fcoefs, ws, out);
}

// Round 15
// 112.229 us; speedup vs baseline: 1.6173x; 1.0120x over previous
//
#include <hip/hip_runtime.h>

// TimeDomainCochleagram: exact chunked scan, 256 segments x 375 samples,
// CHANNEL-PACKED: block = (batch b, channel-pair cp) handles channels
// cp and cp+20; lane g owns segment g for both channels as f32x2.
// Round-14 deltas vs round-13 (56us main, 55% stall):
//   1) scan matrices staged to LDS (global loads issued at entry, latency
//      hidden under pass 1; scan reads = uniform ds_read broadcast) -- kills
//      the per-level SMEM wait chain (16 levels x ~200-500cy).
//   2) x stream triple-buffered (prefetch distance 2 macro-groups ~1020cy
//      > ~900cy HBM first-touch latency; 1 wave/SIMD has no TLP to hide it).
// Arithmetic is bitwise-identical to round 13 (absmax 0.0009765625).

typedef float f32x2 __attribute__((ext_vector_type(2)));

#define NCH  40
#define NB   8
#define NCP  20            // channel pairs: (cp, cp+20)
#define TS   96000
#define DOWN 24
#define NSEG 256
#define SEG  375
#define TD   4000
#define NLVL 8
#define INV24 (1.0f/24.0f)

typedef double DMat[4][4][2][2];   // 2x2 blocks; only j<=i used

__device__ __forceinline__ void dmatcopy(DMat dst, const DMat src) {
    #pragma unroll
    for (int i = 0; i < 4; i++)
        #pragma unroll
        for (int j = 0; j < 4; j++) if (j <= i)
            #pragma unroll
            for (int r = 0; r < 2; r++)
                #pragma unroll
                for (int c = 0; c < 2; c++)
                    dst[i][j][r][c] = src[i][j][r][c];
}

__device__ __forceinline__ void dmatmul(DMat C, const DMat A, const DMat B) {
    #pragma unroll
    for (int i = 0; i < 4; i++)
        #pragma unroll
        for (int j = 0; j < 4; j++) if (j <= i)
            #pragma unroll
            for (int r = 0; r < 2; r++)
                #pragma unroll
                for (int c = 0; c < 2; c++) {
                    double acc = 0.0;
                    #pragma unroll
                    for (int k = 0; k < 4; k++) if (k >= j && k <= i)
                        #pragma unroll
                        for (int q = 0; q < 2; q++)
                            acc += A[i][k][r][q] * B[k][j][q][c];
                    C[i][j][r][c] = acc;
                }
}

// ---------- setup: Mk = A^(375*2^k), k=0..7, fp64 (proven, verbatim) ----------
__global__ __launch_bounds__(64)
void cochlea_setup(const float* __restrict__ fcoefs, double* __restrict__ ws)
{
    const int c = (int)threadIdx.x;
    if (c >= NCH) return;
    const float* fc = fcoefs + c * 10;
    const double a0  = (double)fc[0];
    const double n11 = (double)fc[2], n12 = (double)fc[3], n13 = (double)fc[4];
    const double nd1 = -(double)fc[7], nd2 = -(double)fc[8];

    double s[8];
    auto step0 = [&]() {     // one cascade step, x = 0, fp64
        double y0 = s[0];
        s[0] = nd1 * y0 + s[1];
        s[1] = nd2 * y0;
        double y1 = a0 * y0 + s[2];
        s[2] = nd1 * y1 + (n11 * y0 + s[3]);
        s[3] = nd2 * y1;
        double y2 = a0 * y1 + s[4];
        s[4] = nd1 * y2 + (n12 * y1 + s[5]);
        s[5] = nd2 * y2;
        double y3 = a0 * y2 + s[6];
        s[6] = nd1 * y3 + (n13 * y2 + s[7]);
        s[7] = nd2 * y3;
    };

    DMat A, P, T;
    #pragma unroll
    for (int j = 0; j < 8; j++) {
        #pragma unroll
        for (int i = 0; i < 8; i++) s[i] = (i == j) ? 1.0 : 0.0;
        step0();
        #pragma unroll
        for (int i = 0; i < 8; i++)
            if ((i >> 1) >= (j >> 1))
                A[i >> 1][j >> 1][i & 1][j & 1] = s[i];
    }

    // P = A^375; 375 = 0b101110111 -> tail bits after MSB: 0,1,1,1,0,1,1,1
    dmatcopy(P, A);
    const int bits[8] = {0, 1, 1, 1, 0, 1, 1, 1};
    #pragma unroll
    for (int t = 0; t < 8; t++) {
        dmatmul(T, P, P);
        if (bits[t]) dmatmul(P, T, A);
        else         dmatcopy(P, T);
    }

    // store levels: Mk = P^(2^k); linear idx = (rb*(rb+1)/2+cb)*4 + ri*2 + ci
    double* o = ws + (size_t)c * (NLVL * 40);
    for (int k = 0; k < NLVL; k++) {
        #pragma unroll
        for (int rb = 0; rb < 4; rb++)
            #pragma unroll
            for (int cb = 0; cb < 4; cb++) if (cb <= rb)
                #pragma unroll
                for (int ri = 0; ri < 2; ri++)
                    #pragma unroll
                    for (int ci = 0; ci < 2; ci++)
                        o[k * 40 + (rb * (rb + 1) / 2 + cb) * 4 + ri * 2 + ci] = P[rb][cb][ri][ci];
        if (k < NLVL - 1) { dmatmul(T, P, P); dmatcopy(P, T); }
    }
}

// ---------- main: packed pass1 -> 2x sequential fp64 KS scan -> packed pass2 ----------
__global__ __launch_bounds__(256, 1)
void cochlea_main(const float* __restrict__ x,
                  const float* __restrict__ fcoefs,
                  const double* __restrict__ ws,
                  float* __restrict__ out)
{
    const int b  = (int)blockIdx.x;
    const int cp = (int)blockIdx.y;          // channel pair: (cp, cp+20)
    const int g  = (int)threadIdx.x;         // segment index 0..255

    // ---- issue the scan-matrix staging loads FIRST (latency hides under
    //      pass 1; 640 doubles total for both channels) ----
    const double* wsA = ws + (size_t)cp * (NLVL * 40);
    const double* wsB = ws + (size_t)(cp + NCP) * (NLVL * 40);
    double m0, m1, m2 = 0.0;
    {
        int i1 = g + 256;
        m0 = wsA[g];                                    // i0 = g in [0,256) < 320
        m1 = (i1 < 320) ? wsA[i1] : wsB[i1 - 320];      // i1 in [256,512)
        if (g < 128) m2 = wsB[g + 192];                 // i2 = g+512 in [512,640)
    }

    const float* fA = fcoefs + cp * 10;
    const float* fB = fcoefs + (cp + NCP) * 10;

    // packed coefficients {channel A, channel B}
    auto mk2 = [](float u, float v) { f32x2 r; r.x = u; r.y = v; return r; };
    const f32x2 va0  = mk2(fA[0], fB[0]);
    const f32x2 vn00 = mk2(fA[0] / fA[9], fB[0] / fB[9]);
    const f32x2 vn10 = mk2(fA[1] / fA[9], fB[1] / fB[9]);
    const f32x2 vn11 = mk2(fA[2], fB[2]);
    const f32x2 vn12 = mk2(fA[3], fB[3]);
    const f32x2 vn13 = mk2(fA[4], fB[4]);
    const f32x2 vnd1 = mk2(-fA[7], -fB[7]);
    const f32x2 vnd2 = mk2(-fA[8], -fB[8]);
    const f32x2 vz   = mk2(0.f, 0.f);

    f32x2 S[8];
    // one packed time-step: same sample x for both channels (a2==0 form)
    auto stepp = [&](float xu) -> f32x2 {
        f32x2 xv = mk2(xu, xu);
        f32x2 y0 = __builtin_elementwise_fma(vn00, xv, S[0]);
        S[0] = __builtin_elementwise_fma(vnd1, y0, __builtin_elementwise_fma(vn10, xv, S[1]));
        S[1] = vnd2 * y0;
        f32x2 y1 = __builtin_elementwise_fma(va0, y0, S[2]);
        S[2] = __builtin_elementwise_fma(vnd1, y1, __builtin_elementwise_fma(vn11, y0, S[3]));
        S[3] = vnd2 * y1;
        f32x2 y2 = __builtin_elementwise_fma(va0, y1, S[4]);
        S[4] = __builtin_elementwise_fma(vnd1, y2, __builtin_elementwise_fma(vn12, y1, S[5]));
        S[5] = vnd2 * y2;
        f32x2 y3 = __builtin_elementwise_fma(va0, y2, S[6]);
        S[6] = __builtin_elementwise_fma(vnd1, y3, __builtin_elementwise_fma(vn13, y2, S[7]));
        S[7] = vnd2 * y3;
        return y3;
    };

    // ONE load stream: 25 macro-groups of 15 samples (5 float3), TRIPLE-buffered
    const float3* xb3 = reinterpret_cast<const float3*>(x + (size_t)b * TS + (size_t)g * SEG);
    float3 bA[5], bB[5], bC[5];
    auto loadg = [&](float3 (&bf)[5], int m) {
        #pragma unroll
        for (int q = 0; q < 5; q++) bf[q] = xb3[m * 5 + q];
    };

    // ---- pass 1: zero state -> packed end state ----
    #pragma unroll
    for (int i = 0; i < 8; i++) S[i] = vz;
    auto c1 = [&](const float3 (&bf)[5]) {
        #pragma unroll
        for (int q = 0; q < 5; q++) { stepp(bf[q].x); stepp(bf[q].y); stepp(bf[q].z); }
    };
    loadg(bA, 0); loadg(bB, 1);
    for (int p = 0; p < 7; p++) {          // groups 0..20, loads 2 ahead
        loadg(bC, 3 * p + 2); c1(bA);
        loadg(bA, 3 * p + 3); c1(bB);
        loadg(bB, 3 * p + 4); c1(bC);
    }
    loadg(bC, 23); c1(bA);                 // group 21
    loadg(bA, 24); c1(bB);                 // group 22
    c1(bC);                                // group 23
    c1(bA);                                // group 24

    // ---- stage scan matrices to LDS (loads long since landed) ----
    __shared__ double Mlds[2 * NLVL * 40];   // [ch*320 + k*40 + idx], 5120 B
    __shared__ double tk[2][NSEG][9];        // ping-pong, pad row to 9 dbl
    Mlds[g] = m0;
    Mlds[g + 256] = m1;
    if (g < 128) Mlds[g + 512] = m2;
    // run_scan's first barrier makes these visible before any read.

    float iA[8], iB[8];

    auto run_scan = [&](int ch, const double (&ei)[8], float (&oi)[8]) {
        int cur = 0;
        #pragma unroll
        for (int i = 0; i < 8; i++) tk[0][g][i] = ei[i];
        __syncthreads();
        double td[8];
        #pragma unroll
        for (int i = 0; i < 8; i++) td[i] = ei[i];
        for (int k = 0; k < NLVL; k++) {
            const double* Mk = &Mlds[ch * 320 + k * 40];   // uniform -> broadcast
            const int d = 1 << k;
            if (g >= d) {
                double pr[8];
                #pragma unroll
                for (int i = 0; i < 8; i++) pr[i] = tk[cur][g - d][i];
                double nt[8];
                #pragma unroll
                for (int rb = 0; rb < 4; rb++)
                    #pragma unroll
                    for (int ri = 0; ri < 2; ri++) {
                        double acc = td[2 * rb + ri];
                        #pragma unroll
                        for (int cb = 0; cb < 4; cb++) if (cb <= rb)
                            #pragma unroll
                            for (int ci = 0; ci < 2; ci++)
                                acc += Mk[(rb * (rb + 1) / 2 + cb) * 4 + ri * 2 + ci] * pr[2 * cb + ci];
                        nt[2 * rb + ri] = acc;
                    }
                #pragma unroll
                for (int i = 0; i < 8; i++) td[i] = nt[i];
            }
            #pragma unroll
            for (int i = 0; i < 8; i++) tk[cur ^ 1][g][i] = td[i];
            __syncthreads();
            cur ^= 1;
        }
        // exclusive: init for segment g = inclusive[g-1]; segment 0 = zero
        #pragma unroll
        for (int i = 0; i < 8; i++) oi[i] = (g == 0) ? 0.f : (float)tk[cur][g - 1][i];
        __syncthreads();    // protect tk before the next scan reuses it
    };

    {
        double e[8];
        #pragma unroll
        for (int i = 0; i < 8; i++) e[i] = (double)S[i].x;
        run_scan(0, e, iA);
        #pragma unroll
        for (int i = 0; i < 8; i++) e[i] = (double)S[i].y;
        run_scan(1, e, iB);
    }

    #pragma unroll
    for (int i = 0; i < 8; i++) S[i] = mk2(iA[i], iB[i]);

    // ---- pass 2: exact init, relu + mean-pool(24), 3-sample boundary logic ----
    const int g8      = g & 7;
    const int offset  = (15 * g8) % 24;          // segment start mod 24
    const int r       = (24 - offset) % 24;      // head length (samples)
    const bool hashead = (offset != 0);
    const int hh      = hashead ? 1 : 0;
    const int w0      = (SEG * g + r) / 24;      // first own full-window index
    const int ph      = (1 + 5 * g8) & 7;        // boundary iff (jj + ph) % 8 == 0
    float* outA = out + ((size_t)b * NCH + cp) * TD;
    float* outB = out + ((size_t)b * NCH + cp + NCP) * TD;

    f32x2 acc = vz, head = vz;
    int kb = 0;

    auto c2 = [&](const float3 (&bf)[5], int m) {
        #pragma unroll
        for (int q = 0; q < 5; q++) {
            float3 v = bf[q];
            acc += __builtin_elementwise_max(stepp(v.x), vz);
            acc += __builtin_elementwise_max(stepp(v.y), vz);
            acc += __builtin_elementwise_max(stepp(v.z), vz);
            int jj = m * 5 + q;
            if (((jj + ph) & 7) == 0) {          // window boundary for this lane
                bool ishead = hashead && (kb == 0);
                if (ishead) head = acc;
                else {
                    int idx = w0 + kb - hh;
                    outA[idx] = acc.x * INV24;
                    outB[idx] = acc.y * INV24;
                }
                kb++;
                acc = vz;
            }
        }
    };
    loadg(bA, 0); loadg(bB, 1);
    for (int p = 0; p < 7; p++) {          // groups 0..20, loads 2 ahead
        loadg(bC, 3 * p + 2); c2(bA, 3 * p);
        loadg(bA, 3 * p + 3); c2(bB, 3 * p + 1);
        loadg(bB, 3 * p + 4); c2(bC, 3 * p + 2);
    }
    loadg(bC, 23); c2(bA, 21);
    loadg(bA, 24); c2(bB, 22);
    c2(bC, 23);
    c2(bA, 24);

    // straddled window: my tail + right neighbor's head. g8==7 lanes (incl.
    // 63/127/191/255) have zero tail -> shfl never crosses a wave boundary.
    float hx = __shfl_down(head.x, 1, 64);
    float hy = __shfl_down(head.y, 1, 64);
    if (g8 != 7) {
        int idx = w0 + kb - hh;
        outA[idx] = (acc.x + hx) * INV24;
        outB[idx] = (acc.y + hy) * INV24;
    }
}

extern "C" void kernel_launch(void* const* d_in, const int* in_sizes, int n_in,
                              void* d_out, int out_size, void* d_ws, size_t ws_size,
                              hipStream_t stream) {
    const float* x      = (const float*)d_in[0];   // (8, 96000) f32
    const float* fcoefs = (const float*)d_in[1];   // (40, 10)  f32
    float* out = (float*)d_out;                    // (8, 40, 4000) f32
    double* ws = (double*)d_ws;                    // 40*8*40 doubles = 100 KB

    cochlea_setup<<<1, 64, 0, stream>>>(fcoefs, ws);
    dim3 grid(NB, NCP);                            // 160 blocks x 4 waves
    cochlea_main<<<grid, 256, 0, stream>>>(x, fcoefs, ws, out);
}